// Round 16
// baseline (15390.085 us; speedup 1.0000x reference)
//
#include <hip/hip_runtime.h>
#include <hip/hip_bf16.h>
#include <stdint.h>

typedef uint16_t u16;
typedef uint32_t u32;
typedef unsigned long long u64;
typedef __attribute__((ext_vector_type(8))) short short8;
typedef __attribute__((ext_vector_type(4))) float f32x4;

// B=32, S=1024, D_IN=256, E=512, H=512, F=2048, O=512
#define NS 1024

__device__ __forceinline__ float bf2f(u16 v) {
  union { u32 u; float f; } x; x.u = ((u32)v) << 16; return x.f;
}
__device__ __forceinline__ u16 f2bf(float f) {
  union { float f; u32 u; } x; x.f = f;
  u32 r = x.u + 0x7FFFu + ((x.u >> 16) & 1u);
  return (u16)(r >> 16);
}
__device__ __forceinline__ u32 relu2bf(u32 x) {
  u32 kill = (((x >> 15) & 1u) * 0x0000FFFFu) | (((x >> 31) & 1u) * 0xFFFF0000u);
  return x & ~kill;
}
__device__ __forceinline__ f32x4 shfl_x4(f32x4 v, int m) {
  f32x4 r;
  r[0] = __shfl_xor(v[0], m); r[1] = __shfl_xor(v[1], m);
  r[2] = __shfl_xor(v[2], m); r[3] = __shfl_xor(v[3], m);
  return r;
}
// fast gate transcendentals: v_exp_f32-based, saturate correctly at +/-inf
__device__ __forceinline__ float fsig(float x) {
  return 1.f / (1.f + __expf(-x));
}
__device__ __forceinline__ float ftanh(float x) {
  float t = __expf(2.f * x);
  return 1.f - 2.f / (t + 1.f);
}

// ---------------- cast f32 -> bf16 (x4 per thread) ----------------
__global__ __launch_bounds__(256) void k_cast(const float* __restrict__ in,
                                              u16* __restrict__ out, int n4) {
  int i = blockIdx.x * 256 + threadIdx.x;
  if (i >= n4) return;
  float4 v = ((const float4*)in)[i];
  ushort4 o;
  o.x = f2bf(v.x); o.y = f2bf(v.y); o.z = f2bf(v.z); o.w = f2bf(v.w);
  ((ushort4*)out)[i] = o;
}

// ---------------- transpose f32[K][N] -> bf16[N][K] ----------------
__global__ __launch_bounds__(256) void k_transpose(const float* __restrict__ in,
                                                   u16* __restrict__ out,
                                                   int K, int N) {
  __shared__ u16 tile[32][33];
  int k0 = blockIdx.x * 32, n0 = blockIdx.y * 32;
  int tid = threadIdx.x;
#pragma unroll
  for (int i = 0; i < 4; i++) {
    int idx = i * 256 + tid;
    int r = idx >> 5, c = idx & 31;
    tile[r][c] = f2bf(in[(size_t)(k0 + r) * N + n0 + c]);
  }
  __syncthreads();
#pragma unroll
  for (int i = 0; i < 4; i++) {
    int idx = i * 256 + tid;
    int r = idx >> 5, c = idx & 31;
    out[(size_t)(n0 + r) * K + k0 + c] = tile[c][r];
  }
}

// ---------------- bf16 MFMA GEMM: C[M,N] = A[M,K] @ Bt[N,K]^T + bias ----------------
template <bool REMAP, bool RELU_A, bool OUTF32>
__global__ __launch_bounds__(256) void k_gemm(const u16* __restrict__ A,
                                              const u16* __restrict__ Bt,
                                              const float* __restrict__ bias,
                                              void* __restrict__ Cout,
                                              int M, int N, int K) {
  __shared__ u16 As[128 * 32];
  __shared__ u16 Bs[128 * 32];
  const int m0 = blockIdx.x * 128, n0 = blockIdx.y * 128;
  const int tid = threadIdx.x;
  const int wave = tid >> 6, lane = tid & 63;
  const int wm = wave >> 1, wn = wave & 1;
  f32x4 acc[4][4] = {};

  for (int kt = 0; kt < K; kt += 32) {
    uint4 av[2], bv[2];
#pragma unroll
    for (int i = 0; i < 2; i++) {
      int idx = i * 256 + tid;
      int r = idx >> 2, ch = idx & 3;
      av[i] = *(const uint4*)(A + (size_t)(m0 + r) * K + kt + ch * 8);
      bv[i] = *(const uint4*)(Bt + (size_t)(n0 + r) * K + kt + ch * 8);
      if (RELU_A) {
        u32* p = (u32*)&av[i];
        p[0] = relu2bf(p[0]); p[1] = relu2bf(p[1]);
        p[2] = relu2bf(p[2]); p[3] = relu2bf(p[3]);
      }
    }
    __syncthreads();
#pragma unroll
    for (int i = 0; i < 2; i++) {
      int idx = i * 256 + tid;
      int r = idx >> 2, ch = idx & 3;
      *(uint4*)(As + r * 32 + ch * 8) = av[i];
      *(uint4*)(Bs + r * 32 + ch * 8) = bv[i];
    }
    __syncthreads();
    short8 af[4], bf[4];
#pragma unroll
    for (int mi = 0; mi < 4; mi++) {
      int row = wm * 64 + mi * 16 + (lane & 15);
      af[mi] = *(const short8*)(As + row * 32 + (lane >> 4) * 8);
    }
#pragma unroll
    for (int ni = 0; ni < 4; ni++) {
      int col = wn * 64 + ni * 16 + (lane & 15);
      bf[ni] = *(const short8*)(Bs + col * 32 + (lane >> 4) * 8);
    }
#pragma unroll
    for (int mi = 0; mi < 4; mi++)
#pragma unroll
      for (int ni = 0; ni < 4; ni++)
        acc[mi][ni] = __builtin_amdgcn_mfma_f32_16x16x32_bf16(af[mi], bf[ni], acc[mi][ni], 0, 0, 0);
  }

#pragma unroll
  for (int mi = 0; mi < 4; mi++)
#pragma unroll
    for (int ni = 0; ni < 4; ni++) {
      int col = n0 + wn * 64 + ni * 16 + (lane & 15);
      float bvad = bias[col];
#pragma unroll
      for (int r = 0; r < 4; r++) {
        int row = m0 + wm * 64 + mi * 16 + (lane >> 4) * 4 + r;
        float v = acc[mi][ni][r] + bvad;
        size_t orow = REMAP ? ((size_t)(row & 1023) * 32 + (size_t)(row >> 10))
                            : (size_t)row;
        if (OUTF32) ((float*)Cout)[orow * N + col] = v;
        else        ((u16*)Cout)[orow * N + col] = f2bf(v);
      }
    }
}

// ---- chunked direct-poll primitives (literal CC at every use: no runtime
//      indexing into register arrays -> no scratch) ----
#define VOLLEY(CC, D, MISS)                                                    \
  do {                                                                         \
    (MISS) = 0;                                                                \
    _Pragma("unroll")                                                          \
    for (int kk = 0; kk < 4; kk++) {                                           \
      _Pragma("unroll")                                                        \
      for (int p = 0; p < 4; p++) {                                            \
        u64 q = __hip_atomic_load(base + (CC)*64 + kk*16 + p,                  \
                                  __ATOMIC_RELAXED, __HIP_MEMORY_SCOPE_AGENT); \
        (D)[kk*4+p] = (u32)q;                                                  \
        if ((u32)(q >> 32) != want) (MISS) |= (1u << (kk*4+p));                \
      }                                                                        \
    }                                                                          \
  } while (0)

#define RETRY(CC, D, MISS)                                                     \
  do {                                                                         \
    while (__any((MISS) != 0u)) {                                              \
      __builtin_amdgcn_s_sleep(1);                                             \
      _Pragma("unroll")                                                        \
      for (int kk = 0; kk < 4; kk++) {                                         \
        _Pragma("unroll")                                                      \
        for (int p = 0; p < 4; p++) {                                          \
          u32 bit = 1u << (kk*4+p);                                            \
          if ((MISS) & bit) {                                                  \
            u64 q = __hip_atomic_load(base + (CC)*64 + kk*16 + p,              \
                                      __ATOMIC_RELAXED,                       \
                                      __HIP_MEMORY_SCOPE_AGENT);               \
            if ((u32)(q >> 32) == want) { (D)[kk*4+p] = (u32)q;                \
                                          (MISS) &= ~bit; }                    \
          }                                                                    \
        }                                                                      \
      }                                                                        \
    }                                                                          \
  } while (0)

#define MFMA4(CC, D)                                                           \
  do {                                                                         \
    _Pragma("unroll")                                                          \
    for (int kk = 0; kk < 4; kk += 2) {                                        \
      union { u32 u[4]; short8 v; } fa, fb;                                    \
      fa.u[0] = (D)[kk*4+0]; fa.u[1] = (D)[kk*4+1];                            \
      fa.u[2] = (D)[kk*4+2]; fa.u[3] = (D)[kk*4+3];                            \
      fb.u[0] = (D)[kk*4+4]; fb.u[1] = (D)[kk*4+5];                            \
      fb.u[2] = (D)[kk*4+6]; fb.u[3] = (D)[kk*4+7];                            \
      a0 = __builtin_amdgcn_mfma_f32_16x16x32_bf16(fa.v, bfh[(CC)*4+kk],   a0, 0, 0, 0); \
      a1 = __builtin_amdgcn_mfma_f32_16x16x32_bf16(fb.v, bfh[(CC)*4+kk+1], a1, 0, 0, 0); \
    }                                                                          \
  } while (0)

// ---------------- persistent one-hop LSTM, chunked DIRECT polling ----------
// 64 blocks x 256 threads; NO LDS, NO barriers. Tagged u64 packets
// {tag=step, 2xbf16} in a depth-2 ring (protocol verified R11-R13/R15).
// Each thread's 4 packets per kc ARE its MFMA A-fragment (r11 mapping).
// 4 chunks of 4 kc, software-pipelined: V0 V1 R0 M0 V2 R1 M1 V3 R2 M2 R3 M3
// -> MFMA on arrived chunks overlaps polling of later chunks; only 2 chunks
// (32 u32) live at once -> no scratch spill (r11/12's failure mode).
// Ring safety per-wave: a wave's h_{s+1} store data-depends on ALL h_s
// packets (full K=512 reduction), so its tag certifies its reads are done.
__global__ __launch_bounds__(256, 1) void k_lstm(
    const u16* __restrict__ Whh_t,    // [2048][512]
    const u16* __restrict__ Wih_t,    // [2048][512]
    const u16* __restrict__ emb,      // [S*B][512] time-major bf16
    const float* __restrict__ b_lstm, // [2048] f32
    u64* __restrict__ hbuf,           // [2][32][256] tagged packets, zeroed
    float* __restrict__ out,          // [S*B][512] f32 (ys)
    float* __restrict__ hn,
    float* __restrict__ cn)
{
  const int blk = blockIdx.x;
  const int tid = threadIdx.x;
  const int wave = tid >> 6, lane = tid & 63;
  const int hc0 = blk * 8;
  const int mt = wave >> 1, nt = wave & 1;
  const int g = (lane >> 2) & 3;
  const int j = lane & 3;
  const int arow = mt * 16 + (lane & 15);
  const int crow0 = mt * 16 + (lane >> 4) * 4;
  const int mycol = hc0 + nt * 4 + j;

  // resident B fragments (z-col = g*512 + hc0 + nt*4 + j; verified R11-R15)
  short8 bfh[16], bfx[16];
  {
    int lc = lane & 15;
    int gcol = (lc >> 2) * 512 + hc0 + nt * 4 + (lc & 3);
    const u16* bh = Whh_t + (size_t)gcol * 512 + (lane >> 4) * 8;
    const u16* bx = Wih_t + (size_t)gcol * 512 + (lane >> 4) * 8;
#pragma unroll
    for (int kc = 0; kc < 16; kc++) {
      bfh[kc] = *(const short8*)(bh + kc * 32);
      bfx[kc] = *(const short8*)(bx + kc * 32);
    }
  }
  const float bz = b_lstm[g * 512 + hc0 + nt * 4 + j];

  f32x4 cst = {0.f, 0.f, 0.f, 0.f}, hst = {0.f, 0.f, 0.f, 0.f};

  // prologue: zx = x_0 @ W_ih
  f32x4 zx0 = {0.f, 0.f, 0.f, 0.f}, zx1 = {0.f, 0.f, 0.f, 0.f};
  {
    const u16* xb = emb + (size_t)arow * 512 + (lane >> 4) * 8;
    short8 af[16];
#pragma unroll
    for (int kc = 0; kc < 16; kc++) af[kc] = *(const short8*)(xb + kc * 32);
#pragma unroll
    for (int kc = 0; kc < 16; kc += 2) {
      zx0 = __builtin_amdgcn_mfma_f32_16x16x32_bf16(af[kc], bfx[kc], zx0, 0, 0, 0);
      zx1 = __builtin_amdgcn_mfma_f32_16x16x32_bf16(af[kc + 1], bfx[kc + 1], zx1, 0, 0, 0);
    }
  }

#pragma unroll 1
  for (int s = 0; s < NS; s++) {
    const u64* base = hbuf + (size_t)(s & 1) * 8192 + (size_t)arow * 256 + (lane >> 4) * 4;
    const u32 want = (u32)s;

    f32x4 a0 = zx0, a1 = zx1;
    u32 dA[16], dB[16];
    u32 mA, mB;

    // software-pipelined chunked poll + MFMA
    VOLLEY(0, dA, mA);
    VOLLEY(1, dB, mB);
    RETRY(0, dA, mA);
    MFMA4(0, dA);
    VOLLEY(2, dA, mA);
    RETRY(1, dB, mB);
    MFMA4(1, dB);
    VOLLEY(3, dB, mB);
    RETRY(2, dA, mA);
    MFMA4(2, dA);
    RETRY(3, dB, mB);
    MFMA4(3, dB);

    // butterfly gate assembly + fast gates
    f32x4 z0;
#pragma unroll
    for (int r = 0; r < 4; r++) z0[r] = a0[r] + a1[r] + bz;
    f32x4 z1 = shfl_x4(z0, 4);
    f32x4 z2 = shfl_x4(z0, 8);
    f32x4 z3 = shfl_x4(z1, 8);
    f32x4 zi_ = (g == 0) ? z0 : (g == 1) ? z1 : (g == 2) ? z2 : z3;
    f32x4 zf_ = (g == 0) ? z1 : (g == 1) ? z0 : (g == 2) ? z3 : z2;
    f32x4 zg_ = (g == 0) ? z2 : (g == 1) ? z3 : (g == 2) ? z0 : z1;
    f32x4 zo_ = (g == 0) ? z3 : (g == 1) ? z2 : (g == 2) ? z1 : z0;
#pragma unroll
    for (int r = 0; r < 4; r++) {
      float ig = fsig(zi_[r]);
      float fg = fsig(zf_[r]);
      float gg = ftanh(zg_[r]);
      float og = fsig(zo_[r]);
      cst[r] = fg * cst[r] + ig * gg;
      hst[r] = og * ftanh(cst[r]);
    }

    // tagged h store (one-hop handoff; issued ASAP)
    {
      u32 pair[4];
#pragma unroll
      for (int r = 0; r < 4; r++) {
        u16 hb = f2bf(hst[r]);
        u32 nb = (u32)(u16)__shfl_xor((int)hb, 1);
        pair[r] = (u32)hb | (nb << 16);
      }
      if (((lane & 15) & 13) == 0) {   // g==0, j even
        u64* dst = hbuf + (size_t)((s + 1) & 1) * 8192 + (size_t)crow0 * 256
                 + (size_t)(blk * 4 + nt * 2 + (j >> 1));
        u64 tag = ((u64)(u32)(s + 1)) << 32;
#pragma unroll
        for (int r = 0; r < 4; r++)
          __hip_atomic_store(dst + (size_t)r * 256, tag | pair[r],
                             __ATOMIC_RELAXED, __HIP_MEMORY_SCOPE_AGENT);
      }
    }

    // ys store
    if (g == 0) {
#pragma unroll
      for (int r = 0; r < 4; r++)
        out[((size_t)s * 32 + crow0 + r) * 512 + mycol] = hst[r];
    }

    // emb prefetch + zx for s+1 (overlaps next step's poll)
    if (s + 1 < NS) {
      const u16* xb = emb + ((size_t)(s + 1) * 32 + arow) * 512 + (lane >> 4) * 8;
      short8 af2[16];
#pragma unroll
      for (int kc = 0; kc < 16; kc++) af2[kc] = *(const short8*)(xb + kc * 32);
      f32x4 t0 = {0.f, 0.f, 0.f, 0.f}, t1 = {0.f, 0.f, 0.f, 0.f};
#pragma unroll
      for (int kc = 0; kc < 16; kc += 2) {
        t0 = __builtin_amdgcn_mfma_f32_16x16x32_bf16(af2[kc], bfx[kc], t0, 0, 0, 0);
        t1 = __builtin_amdgcn_mfma_f32_16x16x32_bf16(af2[kc + 1], bfx[kc + 1], t1, 0, 0, 0);
      }
      zx0 = t0; zx1 = t1;
    }
  }

  if (g == 0) {
#pragma unroll
    for (int r = 0; r < 4; r++) {
      hn[(size_t)(crow0 + r) * 512 + mycol] = hst[r];
      cn[(size_t)(crow0 + r) * 512 + mycol] = cst[r];
    }
  }
}

extern "C" void kernel_launch(void* const* d_in, const int* in_sizes, int n_in,
                              void* d_out, int out_size, void* d_ws, size_t ws_size,
                              hipStream_t stream) {
  (void)in_sizes; (void)n_in; (void)out_size; (void)ws_size;
  const float* x      = (const float*)d_in[0];
  const float* W_enc  = (const float*)d_in[1];
  const float* b_enc  = (const float*)d_in[2];
  const float* W_ih   = (const float*)d_in[3];
  const float* W_hh   = (const float*)d_in[4];
  const float* b_lstm = (const float*)d_in[5];
  const float* W1     = (const float*)d_in[6];
  const float* b1     = (const float*)d_in[7];
  const float* W2     = (const float*)d_in[8];
  const float* b2     = (const float*)d_in[9];

  char* ws = (char*)d_ws;
  size_t off = 0;
  auto alloc = [&](size_t bytes) -> void* {
    void* p = ws + off;
    off += (bytes + 255) & ~(size_t)255;
    return p;
  };
  u64* hbuf   = (u64*)alloc((size_t)2 * 32 * 256 * 8);  // 128 KB tagged h ring
  u16* Wenc_t = (u16*)alloc((size_t)512 * 256 * 2);
  u16* Wih_t  = (u16*)alloc((size_t)2048 * 512 * 2);
  u16* Whh_t  = (u16*)alloc((size_t)2048 * 512 * 2);
  u16* W1_t   = (u16*)alloc((size_t)2048 * 512 * 2);
  u16* W2_t   = (u16*)alloc((size_t)512 * 2048 * 2);
  u16* big    = (u16*)alloc((size_t)8192 * 2048 * 2);
  u16* xbf    = big;
  u16* T      = big;

  // d_out is F32: ys[S*B*H] | h_n[B*H] | c_n[B*H] | embed_out[S*B*O]
  float* outp = (float*)d_out;
  float* hnp  = outp + (size_t)16777216;
  float* cnp  = hnp + 16384;
  float* eop  = cnp + 16384;
  u16* emb  = (u16*)(eop + 8388608);  // 2nd half of embed_out region

  hipMemsetAsync(hbuf, 0, (size_t)2 * 32 * 256 * 8, stream);

  k_cast<<<8192, 256, 0, stream>>>(x, xbf, 2097152);
  k_transpose<<<dim3(8, 16), 256, 0, stream>>>(W_enc, Wenc_t, 256, 512);
  k_transpose<<<dim3(16, 64), 256, 0, stream>>>(W_ih, Wih_t, 512, 2048);
  k_transpose<<<dim3(16, 64), 256, 0, stream>>>(W_hh, Whh_t, 512, 2048);
  k_transpose<<<dim3(16, 64), 256, 0, stream>>>(W1, W1_t, 512, 2048);
  k_transpose<<<dim3(64, 16), 256, 0, stream>>>(W2, W2_t, 2048, 512);

  k_gemm<true, false, false><<<dim3(256, 4), 256, 0, stream>>>(
      xbf, Wenc_t, b_enc, emb, 32768, 512, 256);

  // recurrence: 64 blocks x 256 threads; cooperative with regular fallback
  {
    void* args[] = {(void*)&Whh_t, (void*)&Wih_t, (void*)&emb, (void*)&b_lstm,
                    (void*)&hbuf, (void*)&outp, (void*)&hnp, (void*)&cnp};
    hipError_t cerr = hipLaunchCooperativeKernel((const void*)k_lstm, dim3(64),
                                                 dim3(256), args, 0, stream);
    if (cerr != hipSuccess) {
      (void)hipGetLastError();
      k_lstm<<<dim3(64), dim3(256), 0, stream>>>(Whh_t, Wih_t, emb, b_lstm,
                                                 hbuf, outp, hnp, cnp);
    }
  }

  for (int cch = 0; cch < 4; cch++) {
    const u16* embc = emb + (size_t)cch * 8192 * 512;
    float* eoc = eop + (size_t)cch * 8192 * 512;
    k_gemm<false, true, false><<<dim3(64, 16), 256, 0, stream>>>(
        embc, W1_t, b1, T, 8192, 2048, 512);
    k_gemm<false, false, true><<<dim3(64, 4), 256, 0, stream>>>(
        T, W2_t, b2, eoc, 8192, 512, 2048);
  }
}

// Round 17
// 9498.186 us; speedup vs baseline: 1.6203x; 1.6203x over previous
//
#include <hip/hip_runtime.h>
#include <hip/hip_bf16.h>
#include <stdint.h>

typedef uint16_t u16;
typedef uint32_t u32;
typedef unsigned long long u64;
typedef __attribute__((ext_vector_type(8))) short short8;
typedef __attribute__((ext_vector_type(4))) float f32x4;

// B=32, S=1024, D_IN=256, E=512, H=512, F=2048, O=512
#define NS 1024

__device__ __forceinline__ float bf2f(u16 v) {
  union { u32 u; float f; } x; x.u = ((u32)v) << 16; return x.f;
}
__device__ __forceinline__ u16 f2bf(float f) {
  union { float f; u32 u; } x; x.f = f;
  u32 r = x.u + 0x7FFFu + ((x.u >> 16) & 1u);
  return (u16)(r >> 16);
}
__device__ __forceinline__ u32 relu2bf(u32 x) {
  u32 kill = (((x >> 15) & 1u) * 0x0000FFFFu) | (((x >> 31) & 1u) * 0xFFFF0000u);
  return x & ~kill;
}
__device__ __forceinline__ f32x4 shfl_x4(f32x4 v, int m) {
  f32x4 r;
  r[0] = __shfl_xor(v[0], m); r[1] = __shfl_xor(v[1], m);
  r[2] = __shfl_xor(v[2], m); r[3] = __shfl_xor(v[3], m);
  return r;
}
// fast gate transcendentals: v_exp_f32-based, saturate correctly at +/-inf
__device__ __forceinline__ float fsig(float x) {
  return 1.f / (1.f + __expf(-x));
}
__device__ __forceinline__ float ftanh(float x) {
  float t = __expf(2.f * x);
  return 1.f - 2.f / (t + 1.f);
}

// ---------------- cast f32 -> bf16 (x4 per thread) ----------------
__global__ __launch_bounds__(256) void k_cast(const float* __restrict__ in,
                                              u16* __restrict__ out, int n4) {
  int i = blockIdx.x * 256 + threadIdx.x;
  if (i >= n4) return;
  float4 v = ((const float4*)in)[i];
  ushort4 o;
  o.x = f2bf(v.x); o.y = f2bf(v.y); o.z = f2bf(v.z); o.w = f2bf(v.w);
  ((ushort4*)out)[i] = o;
}

// ---------------- transpose f32[K][N] -> bf16[N][K] ----------------
__global__ __launch_bounds__(256) void k_transpose(const float* __restrict__ in,
                                                   u16* __restrict__ out,
                                                   int K, int N) {
  __shared__ u16 tile[32][33];
  int k0 = blockIdx.x * 32, n0 = blockIdx.y * 32;
  int tid = threadIdx.x;
#pragma unroll
  for (int i = 0; i < 4; i++) {
    int idx = i * 256 + tid;
    int r = idx >> 5, c = idx & 31;
    tile[r][c] = f2bf(in[(size_t)(k0 + r) * N + n0 + c]);
  }
  __syncthreads();
#pragma unroll
  for (int i = 0; i < 4; i++) {
    int idx = i * 256 + tid;
    int r = idx >> 5, c = idx & 31;
    out[(size_t)(n0 + r) * K + k0 + c] = tile[c][r];
  }
}

// ---------------- bf16 MFMA GEMM: C[M,N] = A[M,K] @ Bt[N,K]^T + bias ----------------
template <bool REMAP, bool RELU_A, bool OUTF32>
__global__ __launch_bounds__(256) void k_gemm(const u16* __restrict__ A,
                                              const u16* __restrict__ Bt,
                                              const float* __restrict__ bias,
                                              void* __restrict__ Cout,
                                              int M, int N, int K) {
  __shared__ u16 As[128 * 32];
  __shared__ u16 Bs[128 * 32];
  const int m0 = blockIdx.x * 128, n0 = blockIdx.y * 128;
  const int tid = threadIdx.x;
  const int wave = tid >> 6, lane = tid & 63;
  const int wm = wave >> 1, wn = wave & 1;
  f32x4 acc[4][4] = {};

  for (int kt = 0; kt < K; kt += 32) {
    uint4 av[2], bv[2];
#pragma unroll
    for (int i = 0; i < 2; i++) {
      int idx = i * 256 + tid;
      int r = idx >> 2, ch = idx & 3;
      av[i] = *(const uint4*)(A + (size_t)(m0 + r) * K + kt + ch * 8);
      bv[i] = *(const uint4*)(Bt + (size_t)(n0 + r) * K + kt + ch * 8);
      if (RELU_A) {
        u32* p = (u32*)&av[i];
        p[0] = relu2bf(p[0]); p[1] = relu2bf(p[1]);
        p[2] = relu2bf(p[2]); p[3] = relu2bf(p[3]);
      }
    }
    __syncthreads();
#pragma unroll
    for (int i = 0; i < 2; i++) {
      int idx = i * 256 + tid;
      int r = idx >> 2, ch = idx & 3;
      *(uint4*)(As + r * 32 + ch * 8) = av[i];
      *(uint4*)(Bs + r * 32 + ch * 8) = bv[i];
    }
    __syncthreads();
    short8 af[4], bf[4];
#pragma unroll
    for (int mi = 0; mi < 4; mi++) {
      int row = wm * 64 + mi * 16 + (lane & 15);
      af[mi] = *(const short8*)(As + row * 32 + (lane >> 4) * 8);
    }
#pragma unroll
    for (int ni = 0; ni < 4; ni++) {
      int col = wn * 64 + ni * 16 + (lane & 15);
      bf[ni] = *(const short8*)(Bs + col * 32 + (lane >> 4) * 8);
    }
#pragma unroll
    for (int mi = 0; mi < 4; mi++)
#pragma unroll
      for (int ni = 0; ni < 4; ni++)
        acc[mi][ni] = __builtin_amdgcn_mfma_f32_16x16x32_bf16(af[mi], bf[ni], acc[mi][ni], 0, 0, 0);
  }

#pragma unroll
  for (int mi = 0; mi < 4; mi++)
#pragma unroll
    for (int ni = 0; ni < 4; ni++) {
      int col = n0 + wn * 64 + ni * 16 + (lane & 15);
      float bvad = bias[col];
#pragma unroll
      for (int r = 0; r < 4; r++) {
        int row = m0 + wm * 64 + mi * 16 + (lane >> 4) * 4 + r;
        float v = acc[mi][ni][r] + bvad;
        size_t orow = REMAP ? ((size_t)(row & 1023) * 32 + (size_t)(row >> 10))
                            : (size_t)row;
        if (OUTF32) ((float*)Cout)[orow * N + col] = v;
        else        ((u16*)Cout)[orow * N + col] = f2bf(v);
      }
    }
}

// ---------------- persistent LSTM: sentinel + fence + PLAIN data ----------
// 64 blocks x 256 threads. h lives as PLAIN bf16 [2][32][512] (depth-2 ring).
// Producer: plain h stores -> __syncthreads (vmcnt drain to L2) -> wave0:
//   fence(release, agent) [L2 writeback] -> sentinel[blk] = s+1 (1 atomic).
// Consumer (per wave, no read-side block barrier): poll 64 sentinels
//   (relaxed atomic, 1 line each) -> fence(acquire, agent) [L2 invalidate]
//   -> PLAIN short8 loads of A-fragments (L3-served, no tags, no LDS).
// Coherent-atomic ops/step: ~16K polls vs r13's 524K data reads.
// Ring safety: sentinel=s+1 data-depends on having read ALL of h_s (full
// K=512 reduction) -> publisher certifies its reads; writer overwrites slot
// only after all sentinels >= s+1. r4's forensics (plain store + threadfence
// pipeline bit-identical to f32-VALU reference) prove gfx950 fence lowering
// does the required L2 wb/inv.
__global__ __launch_bounds__(256, 1) void k_lstm(
    const u16* __restrict__ Whh_t,    // [2048][512]
    const u16* __restrict__ Wih_t,    // [2048][512]
    const u16* __restrict__ emb,      // [S*B][512] time-major bf16
    const float* __restrict__ b_lstm, // [2048] f32
    u16* __restrict__ hbuf,           // [2][32][512] plain bf16, zeroed
    u32* __restrict__ sent,           // [64*32] zeroed, 128B stride
    float* __restrict__ out,          // [S*B][512] f32 (ys)
    float* __restrict__ hn,
    float* __restrict__ cn)
{
  const int blk = blockIdx.x;
  const int tid = threadIdx.x;
  const int wave = tid >> 6, lane = tid & 63;
  const int hc0 = blk * 8;
  const int mt = wave >> 1, nt = wave & 1;
  const int g = (lane >> 2) & 3;
  const int j = lane & 3;
  const int arow = mt * 16 + (lane & 15);
  const int crow0 = mt * 16 + (lane >> 4) * 4;
  const int mycol = hc0 + nt * 4 + j;

  // resident B fragments (z-col = g*512 + hc0 + nt*4 + j; verified R11-R15)
  short8 bfh[16], bfx[16];
  {
    int lc = lane & 15;
    int gcol = (lc >> 2) * 512 + hc0 + nt * 4 + (lc & 3);
    const u16* bh = Whh_t + (size_t)gcol * 512 + (lane >> 4) * 8;
    const u16* bx = Wih_t + (size_t)gcol * 512 + (lane >> 4) * 8;
#pragma unroll
    for (int kc = 0; kc < 16; kc++) {
      bfh[kc] = *(const short8*)(bh + kc * 32);
      bfx[kc] = *(const short8*)(bx + kc * 32);
    }
  }
  const float bz = b_lstm[g * 512 + hc0 + nt * 4 + j];

  f32x4 cst = {0.f, 0.f, 0.f, 0.f}, hst = {0.f, 0.f, 0.f, 0.f};

  // prologue: zx = x_0 @ W_ih
  f32x4 zx0 = {0.f, 0.f, 0.f, 0.f}, zx1 = {0.f, 0.f, 0.f, 0.f};
  {
    const u16* xb = emb + (size_t)arow * 512 + (lane >> 4) * 8;
    short8 af[16];
#pragma unroll
    for (int kc = 0; kc < 16; kc++) af[kc] = *(const short8*)(xb + kc * 32);
#pragma unroll
    for (int kc = 0; kc < 16; kc += 2) {
      zx0 = __builtin_amdgcn_mfma_f32_16x16x32_bf16(af[kc], bfx[kc], zx0, 0, 0, 0);
      zx1 = __builtin_amdgcn_mfma_f32_16x16x32_bf16(af[kc + 1], bfx[kc + 1], zx1, 0, 0, 0);
    }
  }

#pragma unroll 1
  for (int s = 0; s < NS; s++) {
    // ---- 1. poll sentinels (per wave; 64 lines, one per producer block) ----
    {
      const u32* sp = sent + (size_t)lane * 32;
      while (true) {
        u32 v = __hip_atomic_load(sp, __ATOMIC_RELAXED, __HIP_MEMORY_SCOPE_AGENT);
        if (__all(v >= (u32)s)) break;
        __builtin_amdgcn_s_sleep(1);
      }
      __builtin_amdgcn_fence(__ATOMIC_ACQUIRE, "agent");  // invalidate L1/L2
    }

    // ---- 2. PLAIN A-fragment loads (L3-served after inv; full width) ----
    const u16* hb = hbuf + (size_t)(s & 1) * 16384 + (size_t)arow * 512 + (lane >> 4) * 8;
    short8 hfr[16];
#pragma unroll
    for (int kc = 0; kc < 16; kc++) hfr[kc] = *(const short8*)(hb + kc * 32);

    // ---- 3. h @ W_hh MFMA ----
    f32x4 a0 = zx0, a1 = zx1;
#pragma unroll
    for (int kc = 0; kc < 16; kc += 2) {
      a0 = __builtin_amdgcn_mfma_f32_16x16x32_bf16(hfr[kc], bfh[kc], a0, 0, 0, 0);
      a1 = __builtin_amdgcn_mfma_f32_16x16x32_bf16(hfr[kc + 1], bfh[kc + 1], a1, 0, 0, 0);
    }

    // ---- 4. butterfly gate assembly + fast gates ----
    f32x4 z0;
#pragma unroll
    for (int r = 0; r < 4; r++) z0[r] = a0[r] + a1[r] + bz;
    f32x4 z1 = shfl_x4(z0, 4);
    f32x4 z2 = shfl_x4(z0, 8);
    f32x4 z3 = shfl_x4(z1, 8);
    f32x4 zi_ = (g == 0) ? z0 : (g == 1) ? z1 : (g == 2) ? z2 : z3;
    f32x4 zf_ = (g == 0) ? z1 : (g == 1) ? z0 : (g == 2) ? z3 : z2;
    f32x4 zg_ = (g == 0) ? z2 : (g == 1) ? z3 : (g == 2) ? z0 : z1;
    f32x4 zo_ = (g == 0) ? z3 : (g == 1) ? z2 : (g == 2) ? z1 : z0;
#pragma unroll
    for (int r = 0; r < 4; r++) {
      float ig = fsig(zi_[r]);
      float fg = fsig(zf_[r]);
      float gg = ftanh(zg_[r]);
      float og = fsig(zo_[r]);
      cst[r] = fg * cst[r] + ig * gg;
      hst[r] = og * ftanh(cst[r]);
    }

    // ---- 5. plain packed h stores (writer lanes: g==0, j even) ----
    {
      u32 pair[4];
#pragma unroll
      for (int r = 0; r < 4; r++) {
        u16 hb2 = f2bf(hst[r]);
        u32 nb = (u32)(u16)__shfl_xor((int)hb2, 1);
        pair[r] = (u32)hb2 | (nb << 16);
      }
      if (((lane & 15) & 13) == 0) {
        u32* dst = (u32*)(hbuf + (size_t)((s + 1) & 1) * 16384
                          + (size_t)crow0 * 512 + mycol);
#pragma unroll
        for (int r = 0; r < 4; r++) dst[(size_t)r * 256] = pair[r];
      }
    }

    // ---- 6. drain + release + sentinel ----
    __syncthreads();   // all waves' stores vmcnt-drained into L2
    if (wave == 0) {
      __builtin_amdgcn_fence(__ATOMIC_RELEASE, "agent");  // L2 writeback
      if (lane == 0)
        __hip_atomic_store(sent + (size_t)blk * 32, (u32)(s + 1),
                           __ATOMIC_RELAXED, __HIP_MEMORY_SCOPE_AGENT);
    }

    // ---- 7. ys store (off the inter-block contract; drains later) ----
    if (g == 0) {
#pragma unroll
      for (int r = 0; r < 4; r++)
        out[((size_t)s * 32 + crow0 + r) * 512 + mycol] = hst[r];
    }

    // ---- 8. emb prefetch + zx for s+1 (overlaps other blocks' polls) ----
    if (s + 1 < NS) {
      const u16* xb = emb + ((size_t)(s + 1) * 32 + arow) * 512 + (lane >> 4) * 8;
      short8 af2[16];
#pragma unroll
      for (int kc = 0; kc < 16; kc++) af2[kc] = *(const short8*)(xb + kc * 32);
      f32x4 t0 = {0.f, 0.f, 0.f, 0.f}, t1 = {0.f, 0.f, 0.f, 0.f};
#pragma unroll
      for (int kc = 0; kc < 16; kc += 2) {
        t0 = __builtin_amdgcn_mfma_f32_16x16x32_bf16(af2[kc], bfx[kc], t0, 0, 0, 0);
        t1 = __builtin_amdgcn_mfma_f32_16x16x32_bf16(af2[kc + 1], bfx[kc + 1], t1, 0, 0, 0);
      }
      zx0 = t0; zx1 = t1;
    }
  }

  if (g == 0) {
#pragma unroll
    for (int r = 0; r < 4; r++) {
      hn[(size_t)(crow0 + r) * 512 + mycol] = hst[r];
      cn[(size_t)(crow0 + r) * 512 + mycol] = cst[r];
    }
  }
}

extern "C" void kernel_launch(void* const* d_in, const int* in_sizes, int n_in,
                              void* d_out, int out_size, void* d_ws, size_t ws_size,
                              hipStream_t stream) {
  (void)in_sizes; (void)n_in; (void)out_size; (void)ws_size;
  const float* x      = (const float*)d_in[0];
  const float* W_enc  = (const float*)d_in[1];
  const float* b_enc  = (const float*)d_in[2];
  const float* W_ih   = (const float*)d_in[3];
  const float* W_hh   = (const float*)d_in[4];
  const float* b_lstm = (const float*)d_in[5];
  const float* W1     = (const float*)d_in[6];
  const float* b1     = (const float*)d_in[7];
  const float* W2     = (const float*)d_in[8];
  const float* b2     = (const float*)d_in[9];

  char* ws = (char*)d_ws;
  size_t off = 0;
  auto alloc = [&](size_t bytes) -> void* {
    void* p = ws + off;
    off += (bytes + 255) & ~(size_t)255;
    return p;
  };
  u16* hbuf   = (u16*)alloc((size_t)2 * 32 * 512 * 2);  // 64 KB plain h ring
  u32* sent   = (u32*)alloc((size_t)64 * 128);          // 8 KB sentinels
  u16* Wenc_t = (u16*)alloc((size_t)512 * 256 * 2);
  u16* Wih_t  = (u16*)alloc((size_t)2048 * 512 * 2);
  u16* Whh_t  = (u16*)alloc((size_t)2048 * 512 * 2);
  u16* W1_t   = (u16*)alloc((size_t)2048 * 512 * 2);
  u16* W2_t   = (u16*)alloc((size_t)512 * 2048 * 2);
  u16* big    = (u16*)alloc((size_t)8192 * 2048 * 2);
  u16* xbf    = big;
  u16* T      = big;

  // d_out is F32: ys[S*B*H] | h_n[B*H] | c_n[B*H] | embed_out[S*B*O]
  float* outp = (float*)d_out;
  float* hnp  = outp + (size_t)16777216;
  float* cnp  = hnp + 16384;
  float* eop  = cnp + 16384;
  u16* emb  = (u16*)(eop + 8388608);  // 2nd half of embed_out region

  // zero h ring (h_0 = 0) + sentinels (contiguous at ws start)
  hipMemsetAsync(ws, 0, (size_t)2 * 32 * 512 * 2 + (size_t)64 * 128, stream);

  k_cast<<<8192, 256, 0, stream>>>(x, xbf, 2097152);
  k_transpose<<<dim3(8, 16), 256, 0, stream>>>(W_enc, Wenc_t, 256, 512);
  k_transpose<<<dim3(16, 64), 256, 0, stream>>>(W_ih, Wih_t, 512, 2048);
  k_transpose<<<dim3(16, 64), 256, 0, stream>>>(W_hh, Whh_t, 512, 2048);
  k_transpose<<<dim3(16, 64), 256, 0, stream>>>(W1, W1_t, 512, 2048);
  k_transpose<<<dim3(64, 16), 256, 0, stream>>>(W2, W2_t, 2048, 512);

  k_gemm<true, false, false><<<dim3(256, 4), 256, 0, stream>>>(
      xbf, Wenc_t, b_enc, emb, 32768, 512, 256);

  // recurrence: 64 blocks x 256 threads; cooperative with regular fallback
  {
    void* args[] = {(void*)&Whh_t, (void*)&Wih_t, (void*)&emb, (void*)&b_lstm,
                    (void*)&hbuf, (void*)&sent, (void*)&outp, (void*)&hnp, (void*)&cnp};
    hipError_t cerr = hipLaunchCooperativeKernel((const void*)k_lstm, dim3(64),
                                                 dim3(256), args, 0, stream);
    if (cerr != hipSuccess) {
      (void)hipGetLastError();
      k_lstm<<<dim3(64), dim3(256), 0, stream>>>(Whh_t, Wih_t, emb, b_lstm,
                                                 hbuf, sent, outp, hnp, cnp);
    }
  }

  for (int cch = 0; cch < 4; cch++) {
    const u16* embc = emb + (size_t)cch * 8192 * 512;
    float* eoc = eop + (size_t)cch * 8192 * 512;
    k_gemm<false, true, false><<<dim3(64, 16), 256, 0, stream>>>(
        embc, W1_t, b1, T, 8192, 2048, 512);
    k_gemm<false, false, true><<<dim3(64, 4), 256, 0, stream>>>(
        T, W2_t, b2, eoc, 8192, 512, 2048);
  }
}

// Round 18
// 5831.566 us; speedup vs baseline: 2.6391x; 1.6288x over previous
//
#include <hip/hip_runtime.h>
#include <hip/hip_bf16.h>
#include <stdint.h>

typedef uint16_t u16;
typedef uint32_t u32;
typedef unsigned long long u64;
typedef __attribute__((ext_vector_type(8))) short short8;
typedef __attribute__((ext_vector_type(4))) float f32x4;

// B=32, S=1024, D_IN=256, E=512, H=512, F=2048, O=512
#define NS 1024

__device__ __forceinline__ float bf2f(u16 v) {
  union { u32 u; float f; } x; x.u = ((u32)v) << 16; return x.f;
}
__device__ __forceinline__ u16 f2bf(float f) {
  union { float f; u32 u; } x; x.f = f;
  u32 r = x.u + 0x7FFFu + ((x.u >> 16) & 1u);
  return (u16)(r >> 16);
}
__device__ __forceinline__ u32 relu2bf(u32 x) {
  u32 kill = (((x >> 15) & 1u) * 0x0000FFFFu) | (((x >> 31) & 1u) * 0xFFFF0000u);
  return x & ~kill;
}
__device__ __forceinline__ f32x4 shfl_x4(f32x4 v, int m) {
  f32x4 r;
  r[0] = __shfl_xor(v[0], m); r[1] = __shfl_xor(v[1], m);
  r[2] = __shfl_xor(v[2], m); r[3] = __shfl_xor(v[3], m);
  return r;
}
// fast gate transcendentals: v_exp_f32-based, saturate correctly at +/-inf
__device__ __forceinline__ float fsig(float x) {
  return 1.f / (1.f + __expf(-x));
}
__device__ __forceinline__ float ftanh(float x) {
  float t = __expf(2.f * x);
  return 1.f - 2.f / (t + 1.f);
}

// ---------------- transpose f32[K][N] -> bf16[N][K] ----------------
__global__ __launch_bounds__(256) void k_transpose(const float* __restrict__ in,
                                                   u16* __restrict__ out,
                                                   int K, int N) {
  __shared__ u16 tile[32][33];
  int k0 = blockIdx.x * 32, n0 = blockIdx.y * 32;
  int tid = threadIdx.x;
#pragma unroll
  for (int i = 0; i < 4; i++) {
    int idx = i * 256 + tid;
    int r = idx >> 5, c = idx & 31;
    tile[r][c] = f2bf(in[(size_t)(k0 + r) * N + n0 + c]);
  }
  __syncthreads();
#pragma unroll
  for (int i = 0; i < 4; i++) {
    int idx = i * 256 + tid;
    int r = idx >> 5, c = idx & 31;
    out[(size_t)(n0 + r) * K + k0 + c] = tile[c][r];
  }
}

// ---------------- bf16 MFMA GEMM: C[M,N] = A[M,K] @ Bt[N,K]^T + bias ----------------
// A_F32: A is f32, cast to bf16 during staging (kills the separate cast pass).
template <bool REMAP, bool RELU_A, bool OUTF32, bool A_F32>
__global__ __launch_bounds__(256) void k_gemm(const void* __restrict__ Av,
                                              const u16* __restrict__ Bt,
                                              const float* __restrict__ bias,
                                              void* __restrict__ Cout,
                                              int M, int N, int K) {
  __shared__ u16 As[128 * 32];
  __shared__ u16 Bs[128 * 32];
  const int m0 = blockIdx.x * 128, n0 = blockIdx.y * 128;
  const int tid = threadIdx.x;
  const int wave = tid >> 6, lane = tid & 63;
  const int wm = wave >> 1, wn = wave & 1;
  f32x4 acc[4][4] = {};

  for (int kt = 0; kt < K; kt += 32) {
    uint4 av[2], bv[2];
#pragma unroll
    for (int i = 0; i < 2; i++) {
      int idx = i * 256 + tid;
      int r = idx >> 2, ch = idx & 3;
      if (A_F32) {
        const float* Af = (const float*)Av;
        const float* p = Af + (size_t)(m0 + r) * K + kt + ch * 8;
        float4 f0 = *(const float4*)p;
        float4 f1 = *(const float4*)(p + 4);
        av[i].x = (u32)f2bf(f0.x) | ((u32)f2bf(f0.y) << 16);
        av[i].y = (u32)f2bf(f0.z) | ((u32)f2bf(f0.w) << 16);
        av[i].z = (u32)f2bf(f1.x) | ((u32)f2bf(f1.y) << 16);
        av[i].w = (u32)f2bf(f1.z) | ((u32)f2bf(f1.w) << 16);
      } else {
        av[i] = *(const uint4*)((const u16*)Av + (size_t)(m0 + r) * K + kt + ch * 8);
      }
      bv[i] = *(const uint4*)(Bt + (size_t)(n0 + r) * K + kt + ch * 8);
      if (RELU_A) {
        u32* p = (u32*)&av[i];
        p[0] = relu2bf(p[0]); p[1] = relu2bf(p[1]);
        p[2] = relu2bf(p[2]); p[3] = relu2bf(p[3]);
      }
    }
    __syncthreads();
#pragma unroll
    for (int i = 0; i < 2; i++) {
      int idx = i * 256 + tid;
      int r = idx >> 2, ch = idx & 3;
      *(uint4*)(As + r * 32 + ch * 8) = av[i];
      *(uint4*)(Bs + r * 32 + ch * 8) = bv[i];
    }
    __syncthreads();
    short8 af[4], bf[4];
#pragma unroll
    for (int mi = 0; mi < 4; mi++) {
      int row = wm * 64 + mi * 16 + (lane & 15);
      af[mi] = *(const short8*)(As + row * 32 + (lane >> 4) * 8);
    }
#pragma unroll
    for (int ni = 0; ni < 4; ni++) {
      int col = wn * 64 + ni * 16 + (lane & 15);
      bf[ni] = *(const short8*)(Bs + col * 32 + (lane >> 4) * 8);
    }
#pragma unroll
    for (int mi = 0; mi < 4; mi++)
#pragma unroll
      for (int ni = 0; ni < 4; ni++)
        acc[mi][ni] = __builtin_amdgcn_mfma_f32_16x16x32_bf16(af[mi], bf[ni], acc[mi][ni], 0, 0, 0);
  }

#pragma unroll
  for (int mi = 0; mi < 4; mi++)
#pragma unroll
    for (int ni = 0; ni < 4; ni++) {
      int col = n0 + wn * 64 + ni * 16 + (lane & 15);
      float bvad = bias[col];
#pragma unroll
      for (int r = 0; r < 4; r++) {
        int row = m0 + wm * 64 + mi * 16 + (lane >> 4) * 4 + r;
        float v = acc[mi][ni][r] + bvad;
        size_t orow = REMAP ? ((size_t)(row & 1023) * 32 + (size_t)(row >> 10))
                            : (size_t)row;
        if (OUTF32) ((float*)Cout)[orow * N + col] = v;
        else        ((u16*)Cout)[orow * N + col] = f2bf(v);
      }
    }
}

// ---------------- fused persistent kernel: LSTM (blk 0-63) + MLP (blk 64-255) ----
// LSTM: r15 body VERBATIM (tagged one-hop ring + swizzled LDS staging + fast
// gates) — best measured structure (5.79 ms).
// MLP: 2048 row-groups of 16; per group fc1 -> LDS T[16][2048] -> fc2 ->
// embed_out. Row-group-local, no cross-block deps; runs on the 192 CUs the
// recurrence can't use, fully hidden under it.
__global__ __launch_bounds__(256, 1) void k_main(
    const u16* __restrict__ Whh_t,    // [2048][512]
    const u16* __restrict__ Wih_t,    // [2048][512]
    const u16* __restrict__ emb,      // [S*B][512] time-major bf16 (ws)
    const float* __restrict__ b_lstm, // [2048] f32
    u64* __restrict__ hbuf,           // [2][32][256] tagged packets, zeroed
    float* __restrict__ out,          // ys f32
    float* __restrict__ hn,
    float* __restrict__ cn,
    const u16* __restrict__ W1t,      // [2048][512]
    const u16* __restrict__ W2t,      // [512][2048]
    const float* __restrict__ b1,     // [2048]
    const float* __restrict__ b2,     // [512]
    float* __restrict__ eop)          // embed_out f32 [32768][512]
{
  __shared__ u16 smem[2 * 32 * 512];   // 64 KB: LSTM h dbuf | MLP T[16][2048]

  const int blk = blockIdx.x;
  const int tid = threadIdx.x;
  const int lane = tid & 63;

  if (blk < 64) {
    // ================= LSTM path (r15 verbatim) =================
    const int wave = tid >> 6;
    const int hc0 = blk * 8;
    const int mt = wave >> 1, nt = wave & 1;
    const int g = (lane >> 2) & 3;
    const int j = lane & 3;
    const int arow = mt * 16 + (lane & 15);
    const int crow0 = mt * 16 + (lane >> 4) * 4;
    const int mycol = hc0 + nt * 4 + j;
    const int srow = tid >> 3;
    const int st8 = tid & 7;

    short8 bfh[16], bfx[16];
    {
      int lc = lane & 15;
      int gcol = (lc >> 2) * 512 + hc0 + nt * 4 + (lc & 3);
      const u16* bh = Whh_t + (size_t)gcol * 512 + (lane >> 4) * 8;
      const u16* bx = Wih_t + (size_t)gcol * 512 + (lane >> 4) * 8;
#pragma unroll
      for (int kc = 0; kc < 16; kc++) {
        bfh[kc] = *(const short8*)(bh + kc * 32);
        bfx[kc] = *(const short8*)(bx + kc * 32);
      }
    }
    const float bz = b_lstm[g * 512 + hc0 + nt * 4 + j];

    f32x4 cst = {0.f, 0.f, 0.f, 0.f}, hst = {0.f, 0.f, 0.f, 0.f};

    f32x4 zx0 = {0.f, 0.f, 0.f, 0.f}, zx1 = {0.f, 0.f, 0.f, 0.f};
    {
      const u16* xb = emb + (size_t)arow * 512 + (lane >> 4) * 8;
      short8 af[16];
#pragma unroll
      for (int kc = 0; kc < 16; kc++) af[kc] = *(const short8*)(xb + kc * 32);
#pragma unroll
      for (int kc = 0; kc < 16; kc += 2) {
        zx0 = __builtin_amdgcn_mfma_f32_16x16x32_bf16(af[kc], bfx[kc], zx0, 0, 0, 0);
        zx1 = __builtin_amdgcn_mfma_f32_16x16x32_bf16(af[kc + 1], bfx[kc + 1], zx1, 0, 0, 0);
      }
    }

    char* ldsb = (char*)smem;

#pragma unroll 1
    for (int s = 0; s < NS; s++) {
      // 1. poll-load full h_s (32 packets/thread), stage into LDS
      {
        const u64* base = hbuf + (size_t)(s & 1) * 8192 + (size_t)srow * 256;
        const u32 want = (u32)s;
        u32 d[32];
        u32 miss = 0;
#pragma unroll
        for (int k = 0; k < 8; k++)
#pragma unroll
          for (int m = 0; m < 4; m++) {
            int i = k * 4 + m;
            int p = (k * 8 + st8) * 4 + m;
            u64 q = __hip_atomic_load(base + p, __ATOMIC_RELAXED, __HIP_MEMORY_SCOPE_AGENT);
            d[i] = (u32)q;
            if ((u32)(q >> 32) != want) miss |= (1u << i);
          }
        while (__any(miss != 0u)) {
          __builtin_amdgcn_s_sleep(1);
#pragma unroll
          for (int k = 0; k < 8; k++)
#pragma unroll
            for (int m = 0; m < 4; m++) {
              int i = k * 4 + m;
              if (miss & (1u << i)) {
                int p = (k * 8 + st8) * 4 + m;
                u64 q = __hip_atomic_load(base + p, __ATOMIC_RELAXED, __HIP_MEMORY_SCOPE_AGENT);
                if ((u32)(q >> 32) == want) { d[i] = (u32)q; miss &= ~(1u << i); }
              }
            }
        }
        char* lw = ldsb + (size_t)(s & 1) * 32768 + (size_t)srow * 1024;
#pragma unroll
        for (int k = 0; k < 8; k++) {
          uint4 v;
          v.x = d[k * 4]; v.y = d[k * 4 + 1]; v.z = d[k * 4 + 2]; v.w = d[k * 4 + 3];
          int slot = k * 8 + st8;
          int sw = (slot & ~7) | ((slot ^ srow) & 7);
          *(uint4*)(lw + sw * 16) = v;
        }
      }
      __syncthreads();

      // 2. h @ W_hh MFMA; A-frags from swizzled LDS
      f32x4 a0 = zx0, a1 = zx1;
      {
        const char* lr = ldsb + (size_t)(s & 1) * 32768 + (size_t)arow * 1024;
#pragma unroll
        for (int kc = 0; kc < 16; kc += 2) {
          int sl0 = kc * 4 + (lane >> 4);
          int sw0 = (sl0 & ~7) | ((sl0 ^ arow) & 7);
          short8 fa = *(const short8*)(lr + sw0 * 16);
          int sl1 = sl0 + 4;
          int sw1 = (sl1 & ~7) | ((sl1 ^ arow) & 7);
          short8 fb = *(const short8*)(lr + sw1 * 16);
          a0 = __builtin_amdgcn_mfma_f32_16x16x32_bf16(fa, bfh[kc], a0, 0, 0, 0);
          a1 = __builtin_amdgcn_mfma_f32_16x16x32_bf16(fb, bfh[kc + 1], a1, 0, 0, 0);
        }
      }

      // 3. butterfly gates (fast)
      f32x4 z0;
#pragma unroll
      for (int r = 0; r < 4; r++) z0[r] = a0[r] + a1[r] + bz;
      f32x4 z1 = shfl_x4(z0, 4);
      f32x4 z2 = shfl_x4(z0, 8);
      f32x4 z3 = shfl_x4(z1, 8);
      f32x4 zi_ = (g == 0) ? z0 : (g == 1) ? z1 : (g == 2) ? z2 : z3;
      f32x4 zf_ = (g == 0) ? z1 : (g == 1) ? z0 : (g == 2) ? z3 : z2;
      f32x4 zg_ = (g == 0) ? z2 : (g == 1) ? z3 : (g == 2) ? z0 : z1;
      f32x4 zo_ = (g == 0) ? z3 : (g == 1) ? z2 : (g == 2) ? z1 : z0;
#pragma unroll
      for (int r = 0; r < 4; r++) {
        float ig = fsig(zi_[r]);
        float fg = fsig(zf_[r]);
        float gg = ftanh(zg_[r]);
        float og = fsig(zo_[r]);
        cst[r] = fg * cst[r] + ig * gg;
        hst[r] = og * ftanh(cst[r]);
      }

      // 4. tagged h store
      {
        u32 pair[4];
#pragma unroll
        for (int r = 0; r < 4; r++) {
          u16 hb = f2bf(hst[r]);
          u32 nb = (u32)(u16)__shfl_xor((int)hb, 1);
          pair[r] = (u32)hb | (nb << 16);
        }
        if (((lane & 15) & 13) == 0) {
          u64* dst = hbuf + (size_t)((s + 1) & 1) * 8192 + (size_t)crow0 * 256
                   + (size_t)(blk * 4 + nt * 2 + (j >> 1));
          u64 tag = ((u64)(u32)(s + 1)) << 32;
#pragma unroll
          for (int r = 0; r < 4; r++)
            __hip_atomic_store(dst + (size_t)r * 256, tag | pair[r],
                               __ATOMIC_RELAXED, __HIP_MEMORY_SCOPE_AGENT);
        }
      }

      // 5. ys store
      if (g == 0) {
#pragma unroll
        for (int r = 0; r < 4; r++)
          out[((size_t)s * 32 + crow0 + r) * 512 + mycol] = hst[r];
      }

      // 6. emb prefetch + zx for s+1
      if (s + 1 < NS) {
        const u16* xb = emb + ((size_t)(s + 1) * 32 + arow) * 512 + (lane >> 4) * 8;
        short8 af2[16];
#pragma unroll
        for (int kc = 0; kc < 16; kc++) af2[kc] = *(const short8*)(xb + kc * 32);
        f32x4 t0 = {0.f, 0.f, 0.f, 0.f}, t1 = {0.f, 0.f, 0.f, 0.f};
#pragma unroll
        for (int kc = 0; kc < 16; kc += 2) {
          t0 = __builtin_amdgcn_mfma_f32_16x16x32_bf16(af2[kc], bfx[kc], t0, 0, 0, 0);
          t1 = __builtin_amdgcn_mfma_f32_16x16x32_bf16(af2[kc + 1], bfx[kc + 1], t1, 0, 0, 0);
        }
        zx0 = t0; zx1 = t1;
      }
    }

    if (g == 0) {
#pragma unroll
      for (int r = 0; r < 4; r++) {
        hn[(size_t)(crow0 + r) * 512 + mycol] = hst[r];
        cn[(size_t)(crow0 + r) * 512 + mycol] = cst[r];
      }
    }
  } else {
    // ================= MLP path (blk 64..255) =================
    const int mlpb = blk - 64;     // 0..191
    const int wv = tid >> 6;       // wave 0..3
    u16* T = smem;                 // [16][2048] bf16 = 64 KB

#pragma unroll 1
    for (int grp = mlpb; grp < 2048; grp += 192) {
      const int r0 = grp * 16;
      __syncthreads();             // previous group's fc2 T-reads complete

      // fc1 A-frags: group's 16 emb rows, relu'd, loaded once
      short8 af[16];
      {
        const u16* ab = emb + (size_t)(r0 + (lane & 15)) * 512 + (lane >> 4) * 8;
#pragma unroll
        for (int kc = 0; kc < 16; kc++) {
          short8 v = *(const short8*)(ab + kc * 32);
          u32* p = (u32*)&v;
          p[0] = relu2bf(p[0]); p[1] = relu2bf(p[1]);
          p[2] = relu2bf(p[2]); p[3] = relu2bf(p[3]);
          af[kc] = v;
        }
      }
      // fc1: 128 col-tiles; wave wv covers [wv*32, wv*32+32)
#pragma unroll 1
      for (int ct = wv * 32; ct < wv * 32 + 32; ct++) {
        const int col = ct * 16 + (lane & 15);
        const u16* bb = W1t + (size_t)col * 512 + (lane >> 4) * 8;
        f32x4 acc = {0.f, 0.f, 0.f, 0.f};
#pragma unroll
        for (int kc = 0; kc < 16; kc++) {
          short8 bv = *(const short8*)(bb + kc * 32);
          acc = __builtin_amdgcn_mfma_f32_16x16x32_bf16(af[kc], bv, acc, 0, 0, 0);
        }
        float bias = b1[col];
#pragma unroll
        for (int r = 0; r < 4; r++) {
          int row = (lane >> 4) * 4 + r;
          T[row * 2048 + col] = f2bf(acc[r] + bias);
        }
      }
      __syncthreads();             // T complete

      // fc2: 32 col-tiles; wave wv covers [wv*8, wv*8+8)
#pragma unroll 1
      for (int ct = wv * 8; ct < wv * 8 + 8; ct++) {
        const int col = ct * 16 + (lane & 15);
        const u16* bb = W2t + (size_t)col * 2048 + (lane >> 4) * 8;
        const u16* ta = T + (size_t)(lane & 15) * 2048 + (lane >> 4) * 8;
        f32x4 acc = {0.f, 0.f, 0.f, 0.f};
#pragma unroll
        for (int kc = 0; kc < 64; kc++) {
          short8 avv = *(const short8*)(ta + kc * 32);
          short8 bvv = *(const short8*)(bb + kc * 32);
          acc = __builtin_amdgcn_mfma_f32_16x16x32_bf16(avv, bvv, acc, 0, 0, 0);
        }
        float bias = b2[col];
#pragma unroll
        for (int r = 0; r < 4; r++) {
          int row = (lane >> 4) * 4 + r;
          eop[(size_t)(r0 + row) * 512 + col] = acc[r] + bias;
        }
      }
    }
  }
}

extern "C" void kernel_launch(void* const* d_in, const int* in_sizes, int n_in,
                              void* d_out, int out_size, void* d_ws, size_t ws_size,
                              hipStream_t stream) {
  (void)in_sizes; (void)n_in; (void)out_size; (void)ws_size;
  const float* x      = (const float*)d_in[0];
  const float* W_enc  = (const float*)d_in[1];
  const float* b_enc  = (const float*)d_in[2];
  const float* W_ih   = (const float*)d_in[3];
  const float* W_hh   = (const float*)d_in[4];
  const float* b_lstm = (const float*)d_in[5];
  const float* W1     = (const float*)d_in[6];
  const float* b1     = (const float*)d_in[7];
  const float* W2     = (const float*)d_in[8];
  const float* b2     = (const float*)d_in[9];

  char* ws = (char*)d_ws;
  size_t off = 0;
  auto alloc = [&](size_t bytes) -> void* {
    void* p = ws + off;
    off += (bytes + 255) & ~(size_t)255;
    return p;
  };
  // total ws ~40.3 MB (proven budget)
  u64* hbuf   = (u64*)alloc((size_t)2 * 32 * 256 * 8);  // 128 KB tagged h ring
  u16* Wenc_t = (u16*)alloc((size_t)512 * 256 * 2);
  u16* Wih_t  = (u16*)alloc((size_t)2048 * 512 * 2);
  u16* Whh_t  = (u16*)alloc((size_t)2048 * 512 * 2);
  u16* W1_t   = (u16*)alloc((size_t)2048 * 512 * 2);
  u16* W2_t   = (u16*)alloc((size_t)512 * 2048 * 2);
  u16* emb    = (u16*)alloc((size_t)32768 * 512 * 2);   // 33.5 MB (ws now)

  // d_out is F32: ys[S*B*H] | h_n[B*H] | c_n[B*H] | embed_out[S*B*O]
  float* outp = (float*)d_out;
  float* hnp  = outp + (size_t)16777216;
  float* cnp  = hnp + 16384;
  float* eop  = cnp + 16384;

  hipMemsetAsync(hbuf, 0, (size_t)2 * 32 * 256 * 8, stream);

  k_transpose<<<dim3(8, 16), 256, 0, stream>>>(W_enc, Wenc_t, 256, 512);
  k_transpose<<<dim3(16, 64), 256, 0, stream>>>(W_ih, Wih_t, 512, 2048);
  k_transpose<<<dim3(16, 64), 256, 0, stream>>>(W_hh, Whh_t, 512, 2048);
  k_transpose<<<dim3(16, 64), 256, 0, stream>>>(W1, W1_t, 512, 2048);
  k_transpose<<<dim3(64, 16), 256, 0, stream>>>(W2, W2_t, 2048, 512);

  // encoder: emb[s*32+b][E] = bf16(x)@W_enc + b_enc  (f32 A cast in staging)
  k_gemm<true, false, false, true><<<dim3(256, 4), 256, 0, stream>>>(
      x, Wenc_t, b_enc, emb, 32768, 512, 256);

  // fused persistent kernel: 64 LSTM blocks + 192 MLP blocks
  {
    void* args[] = {(void*)&Whh_t, (void*)&Wih_t, (void*)&emb, (void*)&b_lstm,
                    (void*)&hbuf, (void*)&outp, (void*)&hnp, (void*)&cnp,
                    (void*)&W1_t, (void*)&W2_t, (void*)&b1, (void*)&b2,
                    (void*)&eop};
    hipError_t cerr = hipLaunchCooperativeKernel((const void*)k_main, dim3(256),
                                                 dim3(256), args, 0, stream);
    if (cerr != hipSuccess) {
      (void)hipGetLastError();
      k_main<<<dim3(256), dim3(256), 0, stream>>>(Whh_t, Wih_t, emb, b_lstm,
                                                  hbuf, outp, hnp, cnp,
                                                  W1_t, W2_t, b1, b2, eop);
    }
  }
}